// Round 1
// baseline (285.936 us; speedup 1.0000x reference)
//
#include <hip/hip_runtime.h>
#include <math.h>

#define L_SEQ 2048
#define DM    256
#define NHEADS 8
#define HDIM  32

constexpr float ATTN_SCALE = 0.17677669529663687f; // 32^-0.5
constexpr float EPS_LN = 1e-5f;

// ---------------------------------------------------------------------------
// Kernel 1: QKV projection  out = x @ W^T + b   (x:[L,256], W:[256,256] row-major)
// 64x64 output tile per 256-thread block, 4x4 micro-tile, k-step 16.
// ---------------------------------------------------------------------------
__global__ __launch_bounds__(256) void gemm_qkv(
    const float* __restrict__ x,
    const float* __restrict__ Wq, const float* __restrict__ bq,
    const float* __restrict__ Wk, const float* __restrict__ bk,
    const float* __restrict__ Wv, const float* __restrict__ bv,
    float* __restrict__ Qo, float* __restrict__ Ko, float* __restrict__ Vo)
{
    const float* W; const float* bvec; float* out;
    if (blockIdx.z == 0)      { W = Wq; bvec = bq; out = Qo; }
    else if (blockIdx.z == 1) { W = Wk; bvec = bk; out = Ko; }
    else                      { W = Wv; bvec = bv; out = Vo; }

    __shared__ float As[16][68];   // [k][row], stride 68 -> b128 reads 2-way max
    __shared__ float Bs[16][68];   // [k][col]
    const int t  = threadIdx.x;
    const int tx = t & 15, ty = t >> 4;
    const int i0 = blockIdx.x * 64;
    const int j0 = blockIdx.y * 64;
    const int lr = t >> 2;           // 0..63 row
    const int lc = (t & 3) * 4;      // 0,4,8,12 k-col

    float acc[4][4] = {};
    for (int kt = 0; kt < DM; kt += 16) {
        __syncthreads();
        float4 av = *(const float4*)&x[(size_t)(i0 + lr) * DM + kt + lc];
        float4 wv = *(const float4*)&W[(size_t)(j0 + lr) * DM + kt + lc];
        As[lc+0][lr] = av.x; As[lc+1][lr] = av.y; As[lc+2][lr] = av.z; As[lc+3][lr] = av.w;
        Bs[lc+0][lr] = wv.x; Bs[lc+1][lr] = wv.y; Bs[lc+2][lr] = wv.z; Bs[lc+3][lr] = wv.w;
        __syncthreads();
#pragma unroll
        for (int kk = 0; kk < 16; ++kk) {
            float4 a4 = *(const float4*)&As[kk][ty * 4];
            float4 b4 = *(const float4*)&Bs[kk][tx * 4];
            float a[4]  = {a4.x, a4.y, a4.z, a4.w};
            float bb[4] = {b4.x, b4.y, b4.z, b4.w};
#pragma unroll
            for (int ii = 0; ii < 4; ++ii)
#pragma unroll
                for (int jj = 0; jj < 4; ++jj)
                    acc[ii][jj] += a[ii] * bb[jj];
        }
    }
    float4 b4 = *(const float4*)&bvec[j0 + tx * 4];
#pragma unroll
    for (int ii = 0; ii < 4; ++ii) {
        float4 o;
        o.x = acc[ii][0] + b4.x;
        o.y = acc[ii][1] + b4.y;
        o.z = acc[ii][2] + b4.z;
        o.w = acc[ii][3] + b4.w;
        *(float4*)&out[(size_t)(i0 + ty * 4 + ii) * DM + j0 + tx * 4] = o;
    }
}

// ---------------------------------------------------------------------------
// Kernel 2: geometric bias  biasS[i,j] = beta * clamp(MLP(dist(i,j)), -10, 0)
// ---------------------------------------------------------------------------
__global__ __launch_bounds__(256) void bias_mlp(
    const float* __restrict__ pts,
    const float* __restrict__ k_w1, const float* __restrict__ k_b1,
    const float* __restrict__ k_w2, const float* __restrict__ k_b2,
    const float* __restrict__ beta_p,
    float* __restrict__ biasS)
{
    __shared__ float w1[32], b1[32], w2[32], extra[2];
    const int t = threadIdx.x;
    if (t < 32) { w1[t] = k_w1[t]; b1[t] = k_b1[t]; w2[t] = k_w2[t]; }
    if (t == 32) extra[0] = k_b2[0];
    if (t == 33) extra[1] = beta_p[0];
    __syncthreads();

    const int i = blockIdx.y;
    const int j = blockIdx.x * 256 + t;
    float xi = pts[i*3+0], yi = pts[i*3+1], zi = pts[i*3+2];
    float xj = pts[j*3+0], yj = pts[j*3+1], zj = pts[j*3+2];
    float dx = xi - xj, dy = yi - yj, dz = zi - zj;
    float sq = dx*dx + dy*dy + dz*dz;
    float dist = sqrtf(sq);                 // sqrtf(0)=0 matches the reference guard
    float s = 0.f;
#pragma unroll
    for (int n = 0; n < 32; ++n) {
        float h = fmaxf(dist * w1[n] + b1[n], 0.f);
        s += h * w2[n];
    }
    s += extra[0];
    s = fminf(fmaxf(s, -10.f), 0.f);
    biasS[(size_t)i * L_SEQ + j] = extra[1] * s;  // pre-multiplied by beta
}

// ---------------------------------------------------------------------------
// Kernel 3: flash attention per (head, 32-row q-tile).
// 256 threads = 16 row-pairs (ty) x 16 key-quads (tx). Q + acc in registers,
// K/V staged transposed [d][k] in LDS, read as float4 over keys.
// ---------------------------------------------------------------------------
__global__ __launch_bounds__(256, 2) void attn_flash(
    const float* __restrict__ Q, const float* __restrict__ K,
    const float* __restrict__ V, const float* __restrict__ biasS,
    float* __restrict__ Aout)
{
    __shared__ float Kt[HDIM][68];
    __shared__ float Vt[HDIM][68];
    const int t  = threadIdx.x;
    const int tx = t & 15;        // keys 4*tx .. 4*tx+3 of each 64-key tile
    const int ty = t >> 4;        // rows 2*ty, 2*ty+1 of the q-tile
    const int h  = blockIdx.y;
    const int q0 = blockIdx.x * 32;
    const int r0 = q0 + ty * 2;

    float q[2][HDIM];
#pragma unroll
    for (int j = 0; j < 2; ++j)
#pragma unroll
        for (int d4 = 0; d4 < 8; ++d4) {
            float4 v = *(const float4*)&Q[(size_t)(r0 + j) * DM + h * HDIM + d4 * 4];
            q[j][d4*4+0] = v.x; q[j][d4*4+1] = v.y; q[j][d4*4+2] = v.z; q[j][d4*4+3] = v.w;
        }

    float acc[2][HDIM];
#pragma unroll
    for (int j = 0; j < 2; ++j)
#pragma unroll
        for (int d = 0; d < HDIM; ++d) acc[j][d] = 0.f;
    float m[2] = {-INFINITY, -INFINITY};
    float l[2] = {0.f, 0.f};

    for (int k0 = 0; k0 < L_SEQ; k0 += 64) {
        __syncthreads();
        // stage K,V tiles transposed: global rows are 128B-aligned slices (h*32 floats)
#pragma unroll
        for (int rep = 0; rep < 2; ++rep) {
            int f  = t + rep * 256;
            int kk = f >> 3;            // 0..63
            int dd = (f & 7) * 4;       // 0..28
            float4 kv = *(const float4*)&K[(size_t)(k0 + kk) * DM + h * HDIM + dd];
            Kt[dd+0][kk] = kv.x; Kt[dd+1][kk] = kv.y; Kt[dd+2][kk] = kv.z; Kt[dd+3][kk] = kv.w;
            float4 vv = *(const float4*)&V[(size_t)(k0 + kk) * DM + h * HDIM + dd];
            Vt[dd+0][kk] = vv.x; Vt[dd+1][kk] = vv.y; Vt[dd+2][kk] = vv.z; Vt[dd+3][kk] = vv.w;
        }
        __syncthreads();

        // scores: 2 rows x 4 keys per thread
        float s0[4] = {0,0,0,0}, s1[4] = {0,0,0,0};
#pragma unroll
        for (int d = 0; d < HDIM; ++d) {
            float4 k4 = *(const float4*)&Kt[d][tx * 4];
            float qa = q[0][d], qb = q[1][d];
            s0[0] += qa * k4.x; s0[1] += qa * k4.y; s0[2] += qa * k4.z; s0[3] += qa * k4.w;
            s1[0] += qb * k4.x; s1[1] += qb * k4.y; s1[2] += qb * k4.z; s1[3] += qb * k4.w;
        }
        float4 bv0 = *(const float4*)&biasS[(size_t)(r0 + 0) * L_SEQ + k0 + tx * 4];
        float4 bv1 = *(const float4*)&biasS[(size_t)(r0 + 1) * L_SEQ + k0 + tx * 4];
        s0[0] = s0[0]*ATTN_SCALE + bv0.x; s0[1] = s0[1]*ATTN_SCALE + bv0.y;
        s0[2] = s0[2]*ATTN_SCALE + bv0.z; s0[3] = s0[3]*ATTN_SCALE + bv0.w;
        s1[0] = s1[0]*ATTN_SCALE + bv1.x; s1[1] = s1[1]*ATTN_SCALE + bv1.y;
        s1[2] = s1[2]*ATTN_SCALE + bv1.z; s1[3] = s1[3]*ATTN_SCALE + bv1.w;

        // online softmax (reductions across the 16 tx lanes of this row group)
        float p0[4], p1[4];
        {
            float mt = fmaxf(fmaxf(s0[0], s0[1]), fmaxf(s0[2], s0[3]));
#pragma unroll
            for (int off = 1; off < 16; off <<= 1) mt = fmaxf(mt, __shfl_xor(mt, off, 16));
            float mn = fmaxf(m[0], mt);
            float alpha = __expf(m[0] - mn);
            p0[0] = __expf(s0[0] - mn); p0[1] = __expf(s0[1] - mn);
            p0[2] = __expf(s0[2] - mn); p0[3] = __expf(s0[3] - mn);
            float lt = p0[0] + p0[1] + p0[2] + p0[3];
#pragma unroll
            for (int off = 1; off < 16; off <<= 1) lt += __shfl_xor(lt, off, 16);
            l[0] = l[0] * alpha + lt;
            m[0] = mn;
#pragma unroll
            for (int d = 0; d < HDIM; ++d) acc[0][d] *= alpha;
        }
        {
            float mt = fmaxf(fmaxf(s1[0], s1[1]), fmaxf(s1[2], s1[3]));
#pragma unroll
            for (int off = 1; off < 16; off <<= 1) mt = fmaxf(mt, __shfl_xor(mt, off, 16));
            float mn = fmaxf(m[1], mt);
            float alpha = __expf(m[1] - mn);
            p1[0] = __expf(s1[0] - mn); p1[1] = __expf(s1[1] - mn);
            p1[2] = __expf(s1[2] - mn); p1[3] = __expf(s1[3] - mn);
            float lt = p1[0] + p1[1] + p1[2] + p1[3];
#pragma unroll
            for (int off = 1; off < 16; off <<= 1) lt += __shfl_xor(lt, off, 16);
            l[1] = l[1] * alpha + lt;
            m[1] = mn;
#pragma unroll
            for (int d = 0; d < HDIM; ++d) acc[1][d] *= alpha;
        }

        // PV accumulate (p stays in registers)
#pragma unroll
        for (int d = 0; d < HDIM; ++d) {
            float4 v4 = *(const float4*)&Vt[d][tx * 4];
            acc[0][d] += p0[0]*v4.x + p0[1]*v4.y + p0[2]*v4.z + p0[3]*v4.w;
            acc[1][d] += p1[0]*v4.x + p1[1]*v4.y + p1[2]*v4.z + p1[3]*v4.w;
        }
    }

    // reduce partial outputs across the 16 tx lanes (butterfly), lane tx==0 writes
#pragma unroll
    for (int j = 0; j < 2; ++j)
#pragma unroll
        for (int d = 0; d < HDIM; ++d) {
#pragma unroll
            for (int off = 1; off < 16; off <<= 1)
                acc[j][d] += __shfl_xor(acc[j][d], off, 16);
        }
    if (tx == 0) {
#pragma unroll
        for (int j = 0; j < 2; ++j) {
            float inv = 1.0f / l[j];
#pragma unroll
            for (int d4 = 0; d4 < 8; ++d4) {
                float4 o;
                o.x = acc[j][d4*4+0] * inv;
                o.y = acc[j][d4*4+1] * inv;
                o.z = acc[j][d4*4+2] * inv;
                o.w = acc[j][d4*4+3] * inv;
                *(float4*)&Aout[(size_t)(r0 + j) * DM + h * HDIM + d4 * 4] = o;
            }
        }
    }
}

// ---------------------------------------------------------------------------
// Kernel 4: output projection + residual  y = A @ Wo^T + bo + x
// ---------------------------------------------------------------------------
__global__ __launch_bounds__(256) void gemm_proj(
    const float* __restrict__ A, const float* __restrict__ W,
    const float* __restrict__ bvec, const float* __restrict__ resid,
    float* __restrict__ out)
{
    __shared__ float As[16][68];
    __shared__ float Bs[16][68];
    const int t  = threadIdx.x;
    const int tx = t & 15, ty = t >> 4;
    const int i0 = blockIdx.x * 64;
    const int j0 = blockIdx.y * 64;
    const int lr = t >> 2;
    const int lc = (t & 3) * 4;

    float acc[4][4] = {};
    for (int kt = 0; kt < DM; kt += 16) {
        __syncthreads();
        float4 av = *(const float4*)&A[(size_t)(i0 + lr) * DM + kt + lc];
        float4 wv = *(const float4*)&W[(size_t)(j0 + lr) * DM + kt + lc];
        As[lc+0][lr] = av.x; As[lc+1][lr] = av.y; As[lc+2][lr] = av.z; As[lc+3][lr] = av.w;
        Bs[lc+0][lr] = wv.x; Bs[lc+1][lr] = wv.y; Bs[lc+2][lr] = wv.z; Bs[lc+3][lr] = wv.w;
        __syncthreads();
#pragma unroll
        for (int kk = 0; kk < 16; ++kk) {
            float4 a4 = *(const float4*)&As[kk][ty * 4];
            float4 b4 = *(const float4*)&Bs[kk][tx * 4];
            float a[4]  = {a4.x, a4.y, a4.z, a4.w};
            float bb[4] = {b4.x, b4.y, b4.z, b4.w};
#pragma unroll
            for (int ii = 0; ii < 4; ++ii)
#pragma unroll
                for (int jj = 0; jj < 4; ++jj)
                    acc[ii][jj] += a[ii] * bb[jj];
        }
    }
    float4 b4 = *(const float4*)&bvec[j0 + tx * 4];
#pragma unroll
    for (int ii = 0; ii < 4; ++ii) {
        const size_t row = (size_t)(i0 + ty * 4 + ii) * DM + j0 + tx * 4;
        float4 r4 = *(const float4*)&resid[row];
        float4 o;
        o.x = acc[ii][0] + b4.x + r4.x;
        o.y = acc[ii][1] + b4.y + r4.y;
        o.z = acc[ii][2] + b4.z + r4.z;
        o.w = acc[ii][3] + b4.w + r4.w;
        *(float4*)&out[row] = o;
    }
}

// ---------------------------------------------------------------------------
// Kernel 5: LayerNorm over D=256 (one 256-thread block per row)
// ---------------------------------------------------------------------------
__global__ __launch_bounds__(256) void ln_rows(
    const float* __restrict__ y, const float* __restrict__ g,
    const float* __restrict__ b, float* __restrict__ out)
{
    __shared__ float red[8];
    const int i = blockIdx.x;
    const int t = threadIdx.x;
    float v = y[(size_t)i * DM + t];

    float s = v;
#pragma unroll
    for (int off = 32; off; off >>= 1) s += __shfl_xor(s, off, 64);
    if ((t & 63) == 0) red[t >> 6] = s;
    __syncthreads();
    float mu = (red[0] + red[1] + red[2] + red[3]) * (1.0f / 256.0f);

    float dv = v - mu;
    float q2 = dv * dv;
#pragma unroll
    for (int off = 32; off; off >>= 1) q2 += __shfl_xor(q2, off, 64);
    if ((t & 63) == 0) red[4 + (t >> 6)] = q2;
    __syncthreads();
    float var = (red[4] + red[5] + red[6] + red[7]) * (1.0f / 256.0f);

    out[(size_t)i * DM + t] = dv * rsqrtf(var + EPS_LN) * g[t] + b[t];
}

// ---------------------------------------------------------------------------
extern "C" void kernel_launch(void* const* d_in, const int* in_sizes, int n_in,
                              void* d_out, int out_size, void* d_ws, size_t ws_size,
                              hipStream_t stream) {
    (void)in_sizes; (void)n_in; (void)out_size; (void)ws_size;
    const float* features = (const float*)d_in[0];
    const float* pointmaps = (const float*)d_in[1];
    const float* Wq = (const float*)d_in[2];  const float* bq = (const float*)d_in[3];
    const float* Wk = (const float*)d_in[4];  const float* bk = (const float*)d_in[5];
    const float* Wv = (const float*)d_in[6];  const float* bv = (const float*)d_in[7];
    const float* Wo = (const float*)d_in[8];  const float* bo = (const float*)d_in[9];
    const float* beta = (const float*)d_in[10];
    const float* k_w1 = (const float*)d_in[11]; const float* k_b1 = (const float*)d_in[12];
    const float* k_w2 = (const float*)d_in[13]; const float* k_b2 = (const float*)d_in[14];
    const float* ln_g = (const float*)d_in[15]; const float* ln_b = (const float*)d_in[16];
    float* out = (float*)d_out;

    // workspace layout (floats): Q,K,V [L*D] each; biasS [L*L]; A [L*D]; ypre [L*D]
    float* ws    = (float*)d_ws;
    float* Q     = ws;
    float* K     = ws + 524288;
    float* V     = ws + 1048576;
    float* biasS = ws + 1572864;
    float* A     = ws + 5767168;
    float* ypre  = ws + 6291456;   // total 6,815,744 floats = 27.3 MB

    gemm_qkv <<<dim3(32, 4, 3), 256, 0, stream>>>(features, Wq, bq, Wk, bk, Wv, bv, Q, K, V);
    bias_mlp <<<dim3(8, 2048),   256, 0, stream>>>(pointmaps, k_w1, k_b1, k_w2, k_b2, beta, biasS);
    attn_flash<<<dim3(64, 8),    256, 0, stream>>>(Q, K, V, biasS, A);
    gemm_proj<<<dim3(32, 4),     256, 0, stream>>>(A, Wo, bo, features, ypre);
    ln_rows  <<<2048,            256, 0, stream>>>(ypre, ln_g, ln_b, out);
}

// Round 2
// 152.433 us; speedup vs baseline: 1.8758x; 1.8758x over previous
//
#include <hip/hip_runtime.h>
#include <math.h>

#define L_SEQ 2048
#define DM    256
#define NH    8
#define HD    32

typedef __attribute__((ext_vector_type(8))) short bf16x8;
typedef __attribute__((ext_vector_type(4))) float f32x4;

__device__ __forceinline__ unsigned short f2bf(float f) {
    unsigned int u = __builtin_bit_cast(unsigned int, f);
    u += 0x7fff + ((u >> 16) & 1);          // RNE (finite values only)
    return (unsigned short)(u >> 16);
}

// ---------------------------------------------------------------------------
// Kernel 0: fp32 -> bf16 conversion of x and the 4 weight matrices
// ---------------------------------------------------------------------------
__global__ __launch_bounds__(256) void cvt_inputs(
    const float* __restrict__ x, const float* __restrict__ wq,
    const float* __restrict__ wk, const float* __restrict__ wv,
    const float* __restrict__ wo,
    unsigned short* __restrict__ xb, unsigned short* __restrict__ wqb,
    unsigned short* __restrict__ wkb, unsigned short* __restrict__ wvb,
    unsigned short* __restrict__ wob)
{
    int e = (blockIdx.x * 256 + threadIdx.x) * 4;   // 786432 total elems
    const float* src; unsigned short* dst; int off;
    if      (e < 524288) { src = x;  dst = xb;  off = e; }
    else if (e < 589824) { src = wq; dst = wqb; off = e - 524288; }
    else if (e < 655360) { src = wk; dst = wkb; off = e - 589824; }
    else if (e < 720896) { src = wv; dst = wvb; off = e - 655360; }
    else                 { src = wo; dst = wob; off = e - 720896; }
    float4 v = *(const float4*)(src + off);
    ushort4 o; o.x = f2bf(v.x); o.y = f2bf(v.y); o.z = f2bf(v.z); o.w = f2bf(v.w);
    *(ushort4*)(dst + off) = o;
}

// ---------------------------------------------------------------------------
// Kernel 1: QKV projection via MFMA. Block = 16 rows x 256 cols, 4 waves
// (each wave 64 cols). out = x @ W^T + b, stored bf16 [L][256].
// ---------------------------------------------------------------------------
__global__ __launch_bounds__(256) void gemm_qkv(
    const unsigned short* __restrict__ xb,
    const unsigned short* __restrict__ wqb, const float* __restrict__ bq,
    const unsigned short* __restrict__ wkb, const float* __restrict__ bk,
    const unsigned short* __restrict__ wvb, const float* __restrict__ bv,
    unsigned short* __restrict__ Qb, unsigned short* __restrict__ Kb,
    unsigned short* __restrict__ Vb)
{
    const unsigned short* Wm; const float* bias; unsigned short* out;
    if (blockIdx.z == 0)      { Wm = wqb; bias = bq; out = Qb; }
    else if (blockIdx.z == 1) { Wm = wkb; bias = bk; out = Kb; }
    else                      { Wm = wvb; bias = bv; out = Vb; }

    const int t = threadIdx.x, w = t >> 6, lane = t & 63, quad = lane >> 4, c = lane & 15;
    const int r0 = blockIdx.x * 16;
    const int c0 = w * 64;

    f32x4 acc[4] = {};
    for (int kt = 0; kt < 8; ++kt) {
        bf16x8 a = *(const bf16x8*)(xb + (size_t)(r0 + c) * DM + kt * 32 + quad * 8);
#pragma unroll
        for (int ct = 0; ct < 4; ++ct) {
            bf16x8 b = *(const bf16x8*)(Wm + (size_t)(c0 + ct * 16 + c) * DM + kt * 32 + quad * 8);
            acc[ct] = __builtin_amdgcn_mfma_f32_16x16x32_bf16(a, b, acc[ct], 0, 0, 0);
        }
    }
#pragma unroll
    for (int ct = 0; ct < 4; ++ct) {
        float bc = bias[c0 + ct * 16 + c];
#pragma unroll
        for (int reg = 0; reg < 4; ++reg) {
            int r = r0 + quad * 4 + reg;
            out[(size_t)r * DM + c0 + ct * 16 + c] = f2bf(acc[ct][reg] + bc);
        }
    }
}

// ---------------------------------------------------------------------------
// Kernel 2: geometric bias. Stores beta*clamp(MLP(dist),-10,0) as bf16 in
// PERMUTED pair layout: position p within each 32-key block maps to key
// (p>>1) + 16*(p&1)  — so keys (c, c+16) sit adjacent (matches S0/S1 frags).
// ---------------------------------------------------------------------------
__global__ __launch_bounds__(256) void bias_mlp(
    const float* __restrict__ pts,
    const float* __restrict__ k_w1, const float* __restrict__ k_b1,
    const float* __restrict__ k_w2, const float* __restrict__ k_b2,
    const float* __restrict__ beta_p,
    unsigned short* __restrict__ biasP)
{
    const int i  = blockIdx.y;
    const int p0 = (blockIdx.x * 256 + threadIdx.x) * 4;
    const float xi = pts[i * 3], yi = pts[i * 3 + 1], zi = pts[i * 3 + 2];
    const float beta = beta_p[0], b2 = k_b2[0];

    float dist[4];
#pragma unroll
    for (int v = 0; v < 4; ++v) {
        int p = p0 + v, loc = p & 31, base = p & ~31;
        int k = base + (loc >> 1) + 16 * (loc & 1);
        float dx = xi - pts[k * 3], dy = yi - pts[k * 3 + 1], dz = zi - pts[k * 3 + 2];
        dist[v] = sqrtf(dx * dx + dy * dy + dz * dz);
    }
    float s[4] = {0.f, 0.f, 0.f, 0.f};
#pragma unroll
    for (int n = 0; n < 32; ++n) {
        float w1 = k_w1[n], b1 = k_b1[n], w2 = k_w2[n];   // uniform -> s_loads
#pragma unroll
        for (int v = 0; v < 4; ++v) s[v] += fmaxf(fmaf(dist[v], w1, b1), 0.f) * w2;
    }
    ushort4 o; unsigned short* po = (unsigned short*)&o;
#pragma unroll
    for (int v = 0; v < 4; ++v)
        po[v] = f2bf(fminf(fmaxf(s[v] + b2, -10.f), 0.f) * beta);
    *(ushort4*)(biasP + (size_t)i * L_SEQ + p0) = o;
}

// ---------------------------------------------------------------------------
// Kernel 3: V transpose to Vt[h*32+d][key'] bf16 with the same key permutation.
// ---------------------------------------------------------------------------
__global__ __launch_bounds__(256) void vt_trans(
    const unsigned short* __restrict__ Vb, unsigned short* __restrict__ Vt)
{
    __shared__ unsigned short Vs[32][36];
    const int t = threadIdx.x;
    const int k0 = blockIdx.x * 32, h = blockIdx.y;
    {
        int key = t >> 3, dg = t & 7;
        ushort4 v = *(const ushort4*)(Vb + (size_t)(k0 + key) * DM + h * HD + dg * 4);
        *(ushort4*)&Vs[key][dg * 4] = v;
    }
    __syncthreads();
    {
        int d = t >> 3, cg = t & 7;     // positions cg*4 .. cg*4+3
        int c0 = cg * 2;
        ushort4 o;
        o.x = Vs[c0][d];      o.y = Vs[c0 + 16][d];
        o.z = Vs[c0 + 1][d];  o.w = Vs[c0 + 17][d];
        *(ushort4*)(Vt + (size_t)(h * HD + d) * L_SEQ + k0 + cg * 4) = o;
    }
}

// ---------------------------------------------------------------------------
// Kernel 4: MFMA flash attention. Block = (32 q-rows, 1 head), 4 waves with
// 4-way key split (512 keys each). Fixed-shift softmax (M=10) -> partials
// combine by plain sums. No __syncthreads in the K-loop; P does a wave-local
// LDS transpose (C-layout -> A-layout) in the permuted key order.
// ---------------------------------------------------------------------------
__global__ __launch_bounds__(256) void attn_mfma(
    const unsigned short* __restrict__ Qb, const unsigned short* __restrict__ Kb,
    const unsigned short* __restrict__ Vt, const unsigned short* __restrict__ biasP,
    unsigned short* __restrict__ Ab)
{
    __shared__ unsigned short Plds[4][32][40];
    __shared__ float Ol[4][32][36];
    __shared__ float Ll[4][32];
    const int t = threadIdx.x, w = t >> 6, lane = t & 63, quad = lane >> 4, c = lane & 15;
    const int h = blockIdx.y, r0 = blockIdx.x * 32;
    const int kbase = w * 512;
    const f32x4 Z = {};

    bf16x8 qf0 = *(const bf16x8*)(Qb + (size_t)(r0 + c) * DM + h * HD + quad * 8);
    bf16x8 qf1 = *(const bf16x8*)(Qb + (size_t)(r0 + 16 + c) * DM + h * HD + quad * 8);

    f32x4 O00 = {}, O01 = {}, O10 = {}, O11 = {};
    float l0[4] = {0.f,0.f,0.f,0.f}, l1[4] = {0.f,0.f,0.f,0.f};

    const float LOG2E = 1.4426950408889634f;
    const float C1 = 0.17677669529663687f * LOG2E;  // SCALE * log2e
    const float MC = -10.0f * LOG2E;                // fixed shift

    const unsigned short* Kp  = Kb + (size_t)h * HD + quad * 8;
    const unsigned short* Vp0 = Vt + (size_t)(h * HD + c) * L_SEQ + quad * 8;
    const unsigned short* Vp1 = Vt + (size_t)(h * HD + 16 + c) * L_SEQ + quad * 8;
    const int br0 = r0 + quad * 4;

    bf16x8 kf0 = *(const bf16x8*)(Kp + (size_t)(kbase + c) * DM);
    bf16x8 kf1 = *(const bf16x8*)(Kp + (size_t)(kbase + 16 + c) * DM);
    bf16x8 vf0 = *(const bf16x8*)(Vp0 + kbase);
    bf16x8 vf1 = *(const bf16x8*)(Vp1 + kbase);
    unsigned int bu0[4], bu1[4];
#pragma unroll
    for (int reg = 0; reg < 4; ++reg) {
        bu0[reg] = *(const unsigned int*)(biasP + (size_t)(br0 + reg) * L_SEQ + kbase + c * 2);
        bu1[reg] = *(const unsigned int*)(biasP + (size_t)(br0 + 16 + reg) * L_SEQ + kbase + c * 2);
    }

    for (int kt = 0; kt < 16; ++kt) {
        const int kn = kbase + (kt + 1) * 32;
        bf16x8 nk0 = kf0, nk1 = kf1, nv0 = vf0, nv1 = vf1;
        unsigned int nbu0[4], nbu1[4];
#pragma unroll
        for (int reg = 0; reg < 4; ++reg) { nbu0[reg] = bu0[reg]; nbu1[reg] = bu1[reg]; }
        if (kt < 15) {   // prefetch next tile's fragments (no barrier in this loop)
            nk0 = *(const bf16x8*)(Kp + (size_t)(kn + c) * DM);
            nk1 = *(const bf16x8*)(Kp + (size_t)(kn + 16 + c) * DM);
            nv0 = *(const bf16x8*)(Vp0 + kn);
            nv1 = *(const bf16x8*)(Vp1 + kn);
#pragma unroll
            for (int reg = 0; reg < 4; ++reg) {
                nbu0[reg] = *(const unsigned int*)(biasP + (size_t)(br0 + reg) * L_SEQ + kn + c * 2);
                nbu1[reg] = *(const unsigned int*)(biasP + (size_t)(br0 + 16 + reg) * L_SEQ + kn + c * 2);
            }
        }

        f32x4 S00 = __builtin_amdgcn_mfma_f32_16x16x32_bf16(qf0, kf0, Z, 0, 0, 0);
        f32x4 S01 = __builtin_amdgcn_mfma_f32_16x16x32_bf16(qf0, kf1, Z, 0, 0, 0);
        f32x4 S10 = __builtin_amdgcn_mfma_f32_16x16x32_bf16(qf1, kf0, Z, 0, 0, 0);
        f32x4 S11 = __builtin_amdgcn_mfma_f32_16x16x32_bf16(qf1, kf1, Z, 0, 0, 0);

#pragma unroll
        for (int reg = 0; reg < 4; ++reg) {
            unsigned int u = bu0[reg];
            float blo = __builtin_bit_cast(float, u << 16);
            float bhi = __builtin_bit_cast(float, u & 0xffff0000u);
            float p0 = __builtin_exp2f(fmaf(S00[reg], C1, fmaf(blo, LOG2E, MC)));
            float p1 = __builtin_exp2f(fmaf(S01[reg], C1, fmaf(bhi, LOG2E, MC)));
            l0[reg] += p0 + p1;
            unsigned int pb = (__builtin_bit_cast(unsigned int, p0) >> 16) |
                              (__builtin_bit_cast(unsigned int, p1) & 0xffff0000u);
            *(unsigned int*)&Plds[w][quad * 4 + reg][c * 2] = pb;

            u = bu1[reg];
            blo = __builtin_bit_cast(float, u << 16);
            bhi = __builtin_bit_cast(float, u & 0xffff0000u);
            p0 = __builtin_exp2f(fmaf(S10[reg], C1, fmaf(blo, LOG2E, MC)));
            p1 = __builtin_exp2f(fmaf(S11[reg], C1, fmaf(bhi, LOG2E, MC)));
            l1[reg] += p0 + p1;
            pb = (__builtin_bit_cast(unsigned int, p0) >> 16) |
                 (__builtin_bit_cast(unsigned int, p1) & 0xffff0000u);
            *(unsigned int*)&Plds[w][16 + quad * 4 + reg][c * 2] = pb;
        }

        bf16x8 pa0 = *(const bf16x8*)&Plds[w][c][quad * 8];
        bf16x8 pa1 = *(const bf16x8*)&Plds[w][16 + c][quad * 8];
        O00 = __builtin_amdgcn_mfma_f32_16x16x32_bf16(pa0, vf0, O00, 0, 0, 0);
        O01 = __builtin_amdgcn_mfma_f32_16x16x32_bf16(pa0, vf1, O01, 0, 0, 0);
        O10 = __builtin_amdgcn_mfma_f32_16x16x32_bf16(pa1, vf0, O10, 0, 0, 0);
        O11 = __builtin_amdgcn_mfma_f32_16x16x32_bf16(pa1, vf1, O11, 0, 0, 0);

        kf0 = nk0; kf1 = nk1; vf0 = nv0; vf1 = nv1;
#pragma unroll
        for (int reg = 0; reg < 4; ++reg) { bu0[reg] = nbu0[reg]; bu1[reg] = nbu1[reg]; }
    }

    // reduce l across the 16 lanes of each quad (rows live per (quad,reg))
#pragma unroll
    for (int off = 1; off < 16; off <<= 1) {
#pragma unroll
        for (int reg = 0; reg < 4; ++reg) {
            l0[reg] += __shfl_xor(l0[reg], off, 16);
            l1[reg] += __shfl_xor(l1[reg], off, 16);
        }
    }
    // dump per-wave partials (plain sums thanks to fixed shift)
#pragma unroll
    for (int reg = 0; reg < 4; ++reg) {
        int row = quad * 4 + reg;
        Ol[w][row][c]           = O00[reg];
        Ol[w][row][16 + c]      = O01[reg];
        Ol[w][row + 16][c]      = O10[reg];
        Ol[w][row + 16][16 + c] = O11[reg];
    }
    if (c == 0) {
#pragma unroll
        for (int reg = 0; reg < 4; ++reg) {
            Ll[w][quad * 4 + reg]      = l0[reg];
            Ll[w][quad * 4 + reg + 16] = l1[reg];
        }
    }
    __syncthreads();
    {
        int row = t >> 3, c4 = (t & 7) * 4;
        float4 a = *(const float4*)&Ol[0][row][c4];
        float4 b = *(const float4*)&Ol[1][row][c4];
        float4 d = *(const float4*)&Ol[2][row][c4];
        float4 e = *(const float4*)&Ol[3][row][c4];
        float inv = 1.0f / (Ll[0][row] + Ll[1][row] + Ll[2][row] + Ll[3][row]);
        ushort4 ob;
        ob.x = f2bf((a.x + b.x + d.x + e.x) * inv);
        ob.y = f2bf((a.y + b.y + d.y + e.y) * inv);
        ob.z = f2bf((a.z + b.z + d.z + e.z) * inv);
        ob.w = f2bf((a.w + b.w + d.w + e.w) * inv);
        *(ushort4*)(Ab + (size_t)(r0 + row) * DM + h * HD + c4) = ob;
    }
}

// ---------------------------------------------------------------------------
// Kernel 5: out-projection + bias + residual + LayerNorm, fused.
// Block = 16 rows x 256 cols (4 waves x 64 cols).
// ---------------------------------------------------------------------------
__global__ __launch_bounds__(256) void proj_ln(
    const unsigned short* __restrict__ Ab, const unsigned short* __restrict__ Wob,
    const float* __restrict__ bo, const float* __restrict__ feat,
    const float* __restrict__ ln_g, const float* __restrict__ ln_b,
    float* __restrict__ out)
{
    __shared__ float red1[4][16], red2[4][16];
    const int t = threadIdx.x, w = t >> 6, lane = t & 63, quad = lane >> 4, c = lane & 15;
    const int r0 = blockIdx.x * 16, c0 = w * 64;

    f32x4 acc[4] = {};
    for (int kt = 0; kt < 8; ++kt) {
        bf16x8 a = *(const bf16x8*)(Ab + (size_t)(r0 + c) * DM + kt * 32 + quad * 8);
#pragma unroll
        for (int ct = 0; ct < 4; ++ct) {
            bf16x8 b = *(const bf16x8*)(Wob + (size_t)(c0 + ct * 16 + c) * DM + kt * 32 + quad * 8);
            acc[ct] = __builtin_amdgcn_mfma_f32_16x16x32_bf16(a, b, acc[ct], 0, 0, 0);
        }
    }
    float y[4][4];
    float s1[4] = {0.f,0.f,0.f,0.f}, s2[4] = {0.f,0.f,0.f,0.f};
#pragma unroll
    for (int ct = 0; ct < 4; ++ct) {
        int col = c0 + ct * 16 + c;
        float bc = bo[col];
#pragma unroll
        for (int reg = 0; reg < 4; ++reg) {
            int r = r0 + quad * 4 + reg;
            float v = acc[ct][reg] + bc + feat[(size_t)r * DM + col];
            y[ct][reg] = v;
            s1[reg] += v; s2[reg] += v * v;
        }
    }
#pragma unroll
    for (int off = 1; off < 16; off <<= 1)
#pragma unroll
        for (int reg = 0; reg < 4; ++reg) {
            s1[reg] += __shfl_xor(s1[reg], off, 16);
            s2[reg] += __shfl_xor(s2[reg], off, 16);
        }
    if (c == 0)
#pragma unroll
        for (int reg = 0; reg < 4; ++reg) {
            red1[w][quad * 4 + reg] = s1[reg];
            red2[w][quad * 4 + reg] = s2[reg];
        }
    __syncthreads();
    float mu[4], rs[4];
#pragma unroll
    for (int reg = 0; reg < 4; ++reg) {
        int row = quad * 4 + reg;
        float a1 = red1[0][row] + red1[1][row] + red1[2][row] + red1[3][row];
        float a2 = red2[0][row] + red2[1][row] + red2[2][row] + red2[3][row];
        float m = a1 * (1.0f / 256.0f);
        mu[reg] = m;
        rs[reg] = rsqrtf(a2 * (1.0f / 256.0f) - m * m + 1e-5f);
    }
#pragma unroll
    for (int ct = 0; ct < 4; ++ct) {
        int col = c0 + ct * 16 + c;
        float g = ln_g[col], bb = ln_b[col];
#pragma unroll
        for (int reg = 0; reg < 4; ++reg) {
            int r = r0 + quad * 4 + reg;
            out[(size_t)r * DM + col] = (y[ct][reg] - mu[reg]) * rs[reg] * g + bb;
        }
    }
}

// ---------------------------------------------------------------------------
extern "C" void kernel_launch(void* const* d_in, const int* in_sizes, int n_in,
                              void* d_out, int out_size, void* d_ws, size_t ws_size,
                              hipStream_t stream) {
    (void)in_sizes; (void)n_in; (void)out_size; (void)ws_size;
    const float* features  = (const float*)d_in[0];
    const float* pointmaps = (const float*)d_in[1];
    const float* Wq = (const float*)d_in[2];  const float* bq = (const float*)d_in[3];
    const float* Wk = (const float*)d_in[4];  const float* bk = (const float*)d_in[5];
    const float* Wv = (const float*)d_in[6];  const float* bv = (const float*)d_in[7];
    const float* Wo = (const float*)d_in[8];  const float* bo = (const float*)d_in[9];
    const float* beta = (const float*)d_in[10];
    const float* k_w1 = (const float*)d_in[11]; const float* k_b1 = (const float*)d_in[12];
    const float* k_w2 = (const float*)d_in[13]; const float* k_b2 = (const float*)d_in[14];
    const float* ln_g = (const float*)d_in[15]; const float* ln_b = (const float*)d_in[16];
    float* out = (float*)d_out;

    char* W = (char*)d_ws;
    unsigned short* xb    = (unsigned short*)(W);
    unsigned short* Wqb   = (unsigned short*)(W + 1048576);
    unsigned short* Wkb   = (unsigned short*)(W + 1179648);
    unsigned short* Wvb   = (unsigned short*)(W + 1310720);
    unsigned short* Wob   = (unsigned short*)(W + 1441792);
    unsigned short* Qb    = (unsigned short*)(W + 1572864);
    unsigned short* Kb    = (unsigned short*)(W + 2621440);
    unsigned short* Vb    = (unsigned short*)(W + 3670016);
    unsigned short* Vt    = (unsigned short*)(W + 4718592);
    unsigned short* Ab    = (unsigned short*)(W + 5767168);
    unsigned short* biasP = (unsigned short*)(W + 6815744);  // 8 MB, ends 15.2 MB

    cvt_inputs<<<768, 256, 0, stream>>>(features, Wq, Wk, Wv, Wo, xb, Wqb, Wkb, Wvb, Wob);
    gemm_qkv  <<<dim3(128, 1, 3), 256, 0, stream>>>(xb, Wqb, bq, Wkb, bk, Wvb, bv, Qb, Kb, Vb);
    bias_mlp  <<<dim3(2, 2048),   256, 0, stream>>>(pointmaps, k_w1, k_b1, k_w2, k_b2, beta, biasP);
    vt_trans  <<<dim3(64, 8),     256, 0, stream>>>(Vb, Vt);
    attn_mfma <<<dim3(64, 8),     256, 0, stream>>>(Qb, Kb, Vt, biasP, Ab);
    proj_ln   <<<128,             256, 0, stream>>>(Ab, Wob, bo, features, ln_g, ln_b, out);
}

// Round 3
// 150.986 us; speedup vs baseline: 1.8938x; 1.0096x over previous
//
#include <hip/hip_runtime.h>
#include <math.h>

#define L_SEQ 2048
#define DM    256
#define NH    8
#define HD    32

typedef __attribute__((ext_vector_type(8))) short bf16x8;
typedef __attribute__((ext_vector_type(4))) float f32x4;

__device__ __forceinline__ unsigned short f2bf(float f) {
    unsigned int u = __builtin_bit_cast(unsigned int, f);
    u += 0x7fff + ((u >> 16) & 1);          // RNE (finite values only)
    return (unsigned short)(u >> 16);
}

// load 8 consecutive fp32, truncate-convert to bf16x8 via v_perm_b32
__device__ __forceinline__ bf16x8 ld8_cvt(const float* __restrict__ p) {
    float4 u = *(const float4*)p;
    float4 v = *(const float4*)(p + 4);
    union { unsigned int i[4]; bf16x8 h; } r;
    r.i[0] = __builtin_amdgcn_perm(__builtin_bit_cast(unsigned int, u.y),
                                   __builtin_bit_cast(unsigned int, u.x), 0x07060302);
    r.i[1] = __builtin_amdgcn_perm(__builtin_bit_cast(unsigned int, u.w),
                                   __builtin_bit_cast(unsigned int, u.z), 0x07060302);
    r.i[2] = __builtin_amdgcn_perm(__builtin_bit_cast(unsigned int, v.y),
                                   __builtin_bit_cast(unsigned int, v.x), 0x07060302);
    r.i[3] = __builtin_amdgcn_perm(__builtin_bit_cast(unsigned int, v.w),
                                   __builtin_bit_cast(unsigned int, v.z), 0x07060302);
    return r.h;
}

// ---------------------------------------------------------------------------
// Kernel 1: fused front end.
//   blocks [0,384):  QKV projection via MFMA, fp32 inputs converted in-kernel.
//                    z = bx>>7 selects Q/K/V; V written TRANSPOSED (Vt[d][key'])
//                    with the permuted key layout (pos = 2*(loc&15)+(loc>>4)).
//   blocks [384,4480): geometric-bias MLP -> biasP bf16, same key permutation.
// ---------------------------------------------------------------------------
__global__ __launch_bounds__(256) void fused_front(
    const float* __restrict__ x, const float* __restrict__ pts,
    const float* __restrict__ Wq, const float* __restrict__ bq,
    const float* __restrict__ Wk, const float* __restrict__ bk,
    const float* __restrict__ Wv, const float* __restrict__ bv,
    const float* __restrict__ k_w1, const float* __restrict__ k_b1,
    const float* __restrict__ k_w2, const float* __restrict__ k_b2,
    const float* __restrict__ beta_p,
    unsigned short* __restrict__ Qb, unsigned short* __restrict__ Kb,
    unsigned short* __restrict__ Vt, unsigned short* __restrict__ biasP)
{
    const int bx = blockIdx.x;
    const int t = threadIdx.x;

    if (bx < 384) {
        const int z  = bx >> 7;
        const int r0 = (bx & 127) << 4;
        const int w = t >> 6, lane = t & 63, quad = lane >> 4, c = lane & 15;
        const int c0 = w * 64;
        const float* Wm  = (z == 0) ? Wq : (z == 1) ? Wk : Wv;
        const float* bia = (z == 0) ? bq : (z == 1) ? bk : bv;

        f32x4 acc[4] = {};
        for (int kt = 0; kt < 8; ++kt) {
            bf16x8 a = ld8_cvt(x + (size_t)(r0 + c) * DM + kt * 32 + quad * 8);
#pragma unroll
            for (int ct = 0; ct < 4; ++ct) {
                bf16x8 b = ld8_cvt(Wm + (size_t)(c0 + ct * 16 + c) * DM + kt * 32 + quad * 8);
                acc[ct] = __builtin_amdgcn_mfma_f32_16x16x32_bf16(a, b, acc[ct], 0, 0, 0);
            }
        }
        if (z < 2) {
            unsigned short* out = (z == 0) ? Qb : Kb;
#pragma unroll
            for (int ct = 0; ct < 4; ++ct) {
                float bc = bia[c0 + ct * 16 + c];
#pragma unroll
                for (int reg = 0; reg < 4; ++reg) {
                    int r = r0 + quad * 4 + reg;
                    out[(size_t)r * DM + c0 + ct * 16 + c] = f2bf(acc[ct][reg] + bc);
                }
            }
        } else {
            // V: write transposed with key permutation. Vt[col][pos], col = h*32+d.
#pragma unroll
            for (int ct = 0; ct < 4; ++ct) {
                int col = c0 + ct * 16 + c;
                float bc = bia[col];
#pragma unroll
                for (int reg = 0; reg < 4; ++reg) {
                    int key = r0 + quad * 4 + reg;
                    int loc = key & 31;
                    int pos = (key & ~31) + 2 * (loc & 15) + (loc >> 4);
                    Vt[(size_t)col * L_SEQ + pos] = f2bf(acc[ct][reg] + bc);
                }
            }
        }
    } else {
        const int b = bx - 384;
        const int i = b >> 1;
        const int p0 = ((b & 1) * 256 + t) * 4;
        const float xi = pts[i * 3], yi = pts[i * 3 + 1], zi = pts[i * 3 + 2];
        const float beta = beta_p[0], b2 = k_b2[0];

        float dist[4];
#pragma unroll
        for (int v = 0; v < 4; ++v) {
            int p = p0 + v, loc = p & 31, base = p & ~31;
            int k = base + (loc >> 1) + 16 * (loc & 1);
            float dx = xi - pts[k * 3], dy = yi - pts[k * 3 + 1], dz = zi - pts[k * 3 + 2];
            dist[v] = sqrtf(dx * dx + dy * dy + dz * dz);
        }
        float s[4] = {0.f, 0.f, 0.f, 0.f};
#pragma unroll
        for (int n = 0; n < 32; ++n) {
            float w1 = k_w1[n], b1 = k_b1[n], w2 = k_w2[n];   // uniform -> s_loads
#pragma unroll
            for (int v = 0; v < 4; ++v) s[v] += fmaxf(fmaf(dist[v], w1, b1), 0.f) * w2;
        }
        ushort4 o; unsigned short* po = (unsigned short*)&o;
#pragma unroll
        for (int v = 0; v < 4; ++v)
            po[v] = f2bf(fminf(fmaxf(s[v] + b2, -10.f), 0.f) * beta);
        *(ushort4*)(biasP + (size_t)i * L_SEQ + p0) = o;
    }
}

// ---------------------------------------------------------------------------
// Kernel 2: MFMA flash attention. Block = (32 q-rows, 1 head), 4 waves with
// 4-way key split (512 keys each). Fixed-shift softmax (M=10) -> partials
// combine by plain sums. No __syncthreads in the K-loop; P does a wave-local
// LDS transpose (C-layout -> A-layout) in the permuted key order.
// ---------------------------------------------------------------------------
__global__ __launch_bounds__(256) void attn_mfma(
    const unsigned short* __restrict__ Qb, const unsigned short* __restrict__ Kb,
    const unsigned short* __restrict__ Vt, const unsigned short* __restrict__ biasP,
    unsigned short* __restrict__ Ab)
{
    __shared__ unsigned short Plds[4][32][40];
    __shared__ float Ol[4][32][36];
    __shared__ float Ll[4][32];
    const int t = threadIdx.x, w = t >> 6, lane = t & 63, quad = lane >> 4, c = lane & 15;
    const int h = blockIdx.y, r0 = blockIdx.x * 32;
    const int kbase = w * 512;
    const f32x4 Z = {};

    bf16x8 qf0 = *(const bf16x8*)(Qb + (size_t)(r0 + c) * DM + h * HD + quad * 8);
    bf16x8 qf1 = *(const bf16x8*)(Qb + (size_t)(r0 + 16 + c) * DM + h * HD + quad * 8);

    f32x4 O00 = {}, O01 = {}, O10 = {}, O11 = {};
    float l0[4] = {0.f,0.f,0.f,0.f}, l1[4] = {0.f,0.f,0.f,0.f};

    const float LOG2E = 1.4426950408889634f;
    const float C1 = 0.17677669529663687f * LOG2E;  // SCALE * log2e
    const float MC = -10.0f * LOG2E;                // fixed shift

    const unsigned short* Kp  = Kb + (size_t)h * HD + quad * 8;
    const unsigned short* Vp0 = Vt + (size_t)(h * HD + c) * L_SEQ + quad * 8;
    const unsigned short* Vp1 = Vt + (size_t)(h * HD + 16 + c) * L_SEQ + quad * 8;
    const int br0 = r0 + quad * 4;

    bf16x8 kf0 = *(const bf16x8*)(Kp + (size_t)(kbase + c) * DM);
    bf16x8 kf1 = *(const bf16x8*)(Kp + (size_t)(kbase + 16 + c) * DM);
    bf16x8 vf0 = *(const bf16x8*)(Vp0 + kbase);
    bf16x8 vf1 = *(const bf16x8*)(Vp1 + kbase);
    unsigned int bu0[4], bu1[4];
#pragma unroll
    for (int reg = 0; reg < 4; ++reg) {
        bu0[reg] = *(const unsigned int*)(biasP + (size_t)(br0 + reg) * L_SEQ + kbase + c * 2);
        bu1[reg] = *(const unsigned int*)(biasP + (size_t)(br0 + 16 + reg) * L_SEQ + kbase + c * 2);
    }

    for (int kt = 0; kt < 16; ++kt) {
        const int kn = kbase + (kt + 1) * 32;
        bf16x8 nk0 = kf0, nk1 = kf1, nv0 = vf0, nv1 = vf1;
        unsigned int nbu0[4], nbu1[4];
#pragma unroll
        for (int reg = 0; reg < 4; ++reg) { nbu0[reg] = bu0[reg]; nbu1[reg] = bu1[reg]; }
        if (kt < 15) {   // prefetch next tile's fragments (no barrier in this loop)
            nk0 = *(const bf16x8*)(Kp + (size_t)(kn + c) * DM);
            nk1 = *(const bf16x8*)(Kp + (size_t)(kn + 16 + c) * DM);
            nv0 = *(const bf16x8*)(Vp0 + kn);
            nv1 = *(const bf16x8*)(Vp1 + kn);
#pragma unroll
            for (int reg = 0; reg < 4; ++reg) {
                nbu0[reg] = *(const unsigned int*)(biasP + (size_t)(br0 + reg) * L_SEQ + kn + c * 2);
                nbu1[reg] = *(const unsigned int*)(biasP + (size_t)(br0 + 16 + reg) * L_SEQ + kn + c * 2);
            }
        }

        f32x4 S00 = __builtin_amdgcn_mfma_f32_16x16x32_bf16(qf0, kf0, Z, 0, 0, 0);
        f32x4 S01 = __builtin_amdgcn_mfma_f32_16x16x32_bf16(qf0, kf1, Z, 0, 0, 0);
        f32x4 S10 = __builtin_amdgcn_mfma_f32_16x16x32_bf16(qf1, kf0, Z, 0, 0, 0);
        f32x4 S11 = __builtin_amdgcn_mfma_f32_16x16x32_bf16(qf1, kf1, Z, 0, 0, 0);

#pragma unroll
        for (int reg = 0; reg < 4; ++reg) {
            unsigned int u = bu0[reg];
            float blo = __builtin_bit_cast(float, u << 16);
            float bhi = __builtin_bit_cast(float, u & 0xffff0000u);
            float p0 = __builtin_exp2f(fmaf(S00[reg], C1, fmaf(blo, LOG2E, MC)));
            float p1 = __builtin_exp2f(fmaf(S01[reg], C1, fmaf(bhi, LOG2E, MC)));
            l0[reg] += p0 + p1;
            unsigned int pb = __builtin_amdgcn_perm(
                __builtin_bit_cast(unsigned int, p1),
                __builtin_bit_cast(unsigned int, p0), 0x07060302);
            *(unsigned int*)&Plds[w][quad * 4 + reg][c * 2] = pb;

            u = bu1[reg];
            blo = __builtin_bit_cast(float, u << 16);
            bhi = __builtin_bit_cast(float, u & 0xffff0000u);
            p0 = __builtin_exp2f(fmaf(S10[reg], C1, fmaf(blo, LOG2E, MC)));
            p1 = __builtin_exp2f(fmaf(S11[reg], C1, fmaf(bhi, LOG2E, MC)));
            l1[reg] += p0 + p1;
            pb = __builtin_amdgcn_perm(
                __builtin_bit_cast(unsigned int, p1),
                __builtin_bit_cast(unsigned int, p0), 0x07060302);
            *(unsigned int*)&Plds[w][16 + quad * 4 + reg][c * 2] = pb;
        }

        bf16x8 pa0 = *(const bf16x8*)&Plds[w][c][quad * 8];
        bf16x8 pa1 = *(const bf16x8*)&Plds[w][16 + c][quad * 8];
        O00 = __builtin_amdgcn_mfma_f32_16x16x32_bf16(pa0, vf0, O00, 0, 0, 0);
        O01 = __builtin_amdgcn_mfma_f32_16x16x32_bf16(pa0, vf1, O01, 0, 0, 0);
        O10 = __builtin_amdgcn_mfma_f32_16x16x32_bf16(pa1, vf0, O10, 0, 0, 0);
        O11 = __builtin_amdgcn_mfma_f32_16x16x32_bf16(pa1, vf1, O11, 0, 0, 0);

        kf0 = nk0; kf1 = nk1; vf0 = nv0; vf1 = nv1;
#pragma unroll
        for (int reg = 0; reg < 4; ++reg) { bu0[reg] = nbu0[reg]; bu1[reg] = nbu1[reg]; }
    }

    // reduce l across the 16 lanes of each quad (rows live per (quad,reg))
#pragma unroll
    for (int off = 1; off < 16; off <<= 1) {
#pragma unroll
        for (int reg = 0; reg < 4; ++reg) {
            l0[reg] += __shfl_xor(l0[reg], off, 16);
            l1[reg] += __shfl_xor(l1[reg], off, 16);
        }
    }
    // dump per-wave partials (plain sums thanks to fixed shift)
#pragma unroll
    for (int reg = 0; reg < 4; ++reg) {
        int row = quad * 4 + reg;
        Ol[w][row][c]           = O00[reg];
        Ol[w][row][16 + c]      = O01[reg];
        Ol[w][row + 16][c]      = O10[reg];
        Ol[w][row + 16][16 + c] = O11[reg];
    }
    if (c == 0) {
#pragma unroll
        for (int reg = 0; reg < 4; ++reg) {
            Ll[w][quad * 4 + reg]      = l0[reg];
            Ll[w][quad * 4 + reg + 16] = l1[reg];
        }
    }
    __syncthreads();
    {
        int row = t >> 3, c4 = (t & 7) * 4;
        float4 a = *(const float4*)&Ol[0][row][c4];
        float4 b = *(const float4*)&Ol[1][row][c4];
        float4 d = *(const float4*)&Ol[2][row][c4];
        float4 e = *(const float4*)&Ol[3][row][c4];
        float inv = 1.0f / (Ll[0][row] + Ll[1][row] + Ll[2][row] + Ll[3][row]);
        ushort4 ob;
        ob.x = f2bf((a.x + b.x + d.x + e.x) * inv);
        ob.y = f2bf((a.y + b.y + d.y + e.y) * inv);
        ob.z = f2bf((a.z + b.z + d.z + e.z) * inv);
        ob.w = f2bf((a.w + b.w + d.w + e.w) * inv);
        *(ushort4*)(Ab + (size_t)(r0 + row) * DM + h * HD + c4) = ob;
    }
}

// ---------------------------------------------------------------------------
// Kernel 3: out-projection + bias + residual + LayerNorm, fused.
// Wo is fp32, converted per-fragment in-kernel. Block = 16 rows x 256 cols.
// ---------------------------------------------------------------------------
__global__ __launch_bounds__(256) void proj_ln(
    const unsigned short* __restrict__ Ab, const float* __restrict__ Wo,
    const float* __restrict__ bo, const float* __restrict__ feat,
    const float* __restrict__ ln_g, const float* __restrict__ ln_b,
    float* __restrict__ out)
{
    __shared__ float red1[4][16], red2[4][16];
    const int t = threadIdx.x, w = t >> 6, lane = t & 63, quad = lane >> 4, c = lane & 15;
    const int r0 = blockIdx.x * 16, c0 = w * 64;

    f32x4 acc[4] = {};
    for (int kt = 0; kt < 8; ++kt) {
        bf16x8 a = *(const bf16x8*)(Ab + (size_t)(r0 + c) * DM + kt * 32 + quad * 8);
#pragma unroll
        for (int ct = 0; ct < 4; ++ct) {
            bf16x8 b = ld8_cvt(Wo + (size_t)(c0 + ct * 16 + c) * DM + kt * 32 + quad * 8);
            acc[ct] = __builtin_amdgcn_mfma_f32_16x16x32_bf16(a, b, acc[ct], 0, 0, 0);
        }
    }
    float y[4][4];
    float s1[4] = {0.f,0.f,0.f,0.f}, s2[4] = {0.f,0.f,0.f,0.f};
#pragma unroll
    for (int ct = 0; ct < 4; ++ct) {
        int col = c0 + ct * 16 + c;
        float bc = bo[col];
#pragma unroll
        for (int reg = 0; reg < 4; ++reg) {
            int r = r0 + quad * 4 + reg;
            float v = acc[ct][reg] + bc + feat[(size_t)r * DM + col];
            y[ct][reg] = v;
            s1[reg] += v; s2[reg] += v * v;
        }
    }
#pragma unroll
    for (int off = 1; off < 16; off <<= 1)
#pragma unroll
        for (int reg = 0; reg < 4; ++reg) {
            s1[reg] += __shfl_xor(s1[reg], off, 16);
            s2[reg] += __shfl_xor(s2[reg], off, 16);
        }
    if (c == 0)
#pragma unroll
        for (int reg = 0; reg < 4; ++reg) {
            red1[w][quad * 4 + reg] = s1[reg];
            red2[w][quad * 4 + reg] = s2[reg];
        }
    __syncthreads();
    float mu[4], rs[4];
#pragma unroll
    for (int reg = 0; reg < 4; ++reg) {
        int row = quad * 4 + reg;
        float a1 = red1[0][row] + red1[1][row] + red1[2][row] + red1[3][row];
        float a2 = red2[0][row] + red2[1][row] + red2[2][row] + red2[3][row];
        float m = a1 * (1.0f / 256.0f);
        mu[reg] = m;
        rs[reg] = rsqrtf(a2 * (1.0f / 256.0f) - m * m + 1e-5f);
    }
#pragma unroll
    for (int ct = 0; ct < 4; ++ct) {
        int col = c0 + ct * 16 + c;
        float g = ln_g[col], bb = ln_b[col];
#pragma unroll
        for (int reg = 0; reg < 4; ++reg) {
            int r = r0 + quad * 4 + reg;
            out[(size_t)r * DM + col] = (y[ct][reg] - mu[reg]) * rs[reg] * g + bb;
        }
    }
}

// ---------------------------------------------------------------------------
extern "C" void kernel_launch(void* const* d_in, const int* in_sizes, int n_in,
                              void* d_out, int out_size, void* d_ws, size_t ws_size,
                              hipStream_t stream) {
    (void)in_sizes; (void)n_in; (void)out_size; (void)ws_size;
    const float* features  = (const float*)d_in[0];
    const float* pointmaps = (const float*)d_in[1];
    const float* Wq = (const float*)d_in[2];  const float* bq = (const float*)d_in[3];
    const float* Wk = (const float*)d_in[4];  const float* bk = (const float*)d_in[5];
    const float* Wv = (const float*)d_in[6];  const float* bv = (const float*)d_in[7];
    const float* Wo = (const float*)d_in[8];  const float* bo = (const float*)d_in[9];
    const float* beta = (const float*)d_in[10];
    const float* k_w1 = (const float*)d_in[11]; const float* k_b1 = (const float*)d_in[12];
    const float* k_w2 = (const float*)d_in[13]; const float* k_b2 = (const float*)d_in[14];
    const float* ln_g = (const float*)d_in[15]; const float* ln_b = (const float*)d_in[16];
    float* out = (float*)d_out;

    char* W = (char*)d_ws;
    unsigned short* Qb    = (unsigned short*)(W);
    unsigned short* Kb    = (unsigned short*)(W + 1048576);
    unsigned short* Vt    = (unsigned short*)(W + 2097152);
    unsigned short* Ab    = (unsigned short*)(W + 3145728);
    unsigned short* biasP = (unsigned short*)(W + 4194304);  // 8 MB, ends 12.6 MB

    fused_front<<<4480, 256, 0, stream>>>(features, pointmaps,
                                          Wq, bq, Wk, bk, Wv, bv,
                                          k_w1, k_b1, k_w2, k_b2, beta,
                                          Qb, Kb, Vt, biasP);
    attn_mfma <<<dim3(64, 8), 256, 0, stream>>>(Qb, Kb, Vt, biasP, Ab);
    proj_ln   <<<128,         256, 0, stream>>>(Ab, Wo, bo, features, ln_g, ln_b, out);
}

// Round 4
// 139.245 us; speedup vs baseline: 2.0535x; 1.0843x over previous
//
#include <hip/hip_runtime.h>
#include <math.h>

#define L_SEQ 2048
#define DM    256
#define NH    8
#define HD    32

typedef __attribute__((ext_vector_type(8))) short bf16x8;
typedef __attribute__((ext_vector_type(4))) float f32x4;

__device__ __forceinline__ unsigned short f2bf(float f) {
    unsigned int u = __builtin_bit_cast(unsigned int, f);
    u += 0x7fff + ((u >> 16) & 1);          // RNE (finite values only)
    return (unsigned short)(u >> 16);
}

// ---------------------------------------------------------------------------
// Kernel 0: prep.
//  blocks [0,384):  fp32 -> bf16 cvt of x, Wq, Wk, Wv, Wo (8 elems/thread)
//  blocks [384,400): bias-MLP lookup table T[4096] over dist in [0,16]
//                    T[n] = beta * clamp(mlp(n/256), -10, 0), fp32.
// ---------------------------------------------------------------------------
__global__ __launch_bounds__(256) void prep(
    const float* __restrict__ x,  const float* __restrict__ wq,
    const float* __restrict__ wk, const float* __restrict__ wv,
    const float* __restrict__ wo,
    const float* __restrict__ k_w1, const float* __restrict__ k_b1,
    const float* __restrict__ k_w2, const float* __restrict__ k_b2,
    const float* __restrict__ beta_p,
    unsigned short* __restrict__ xb,  unsigned short* __restrict__ wqb,
    unsigned short* __restrict__ wkb, unsigned short* __restrict__ wvb,
    unsigned short* __restrict__ wob, float* __restrict__ T)
{
    const int bx = blockIdx.x, t = threadIdx.x;
    if (bx < 384) {
        int e = (bx * 256 + t) * 8;   // 786432 total elems
        const float* src; unsigned short* dst; int off;
        if      (e < 524288) { src = x;  dst = xb;  off = e; }
        else if (e < 589824) { src = wq; dst = wqb; off = e - 524288; }
        else if (e < 655360) { src = wk; dst = wkb; off = e - 589824; }
        else if (e < 720896) { src = wv; dst = wvb; off = e - 655360; }
        else                 { src = wo; dst = wob; off = e - 720896; }
        float4 u = *(const float4*)(src + off);
        float4 v = *(const float4*)(src + off + 4);
        ushort4 a, b;
        a.x = f2bf(u.x); a.y = f2bf(u.y); a.z = f2bf(u.z); a.w = f2bf(u.w);
        b.x = f2bf(v.x); b.y = f2bf(v.y); b.z = f2bf(v.z); b.w = f2bf(v.w);
        *(ushort4*)(dst + off)     = a;
        *(ushort4*)(dst + off + 4) = b;
    } else {
        int n = (bx - 384) * 256 + t;            // 0..4095
        float d = (float)n * (1.0f / 256.0f);
        float s = 0.f;
#pragma unroll
        for (int k = 0; k < 32; ++k)
            s += fmaxf(fmaf(d, k_w1[k], k_b1[k]), 0.f) * k_w2[k];
        s = fminf(fmaxf(s + k_b2[0], -10.f), 0.f);
        T[n] = beta_p[0] * s;
    }
}

// ---------------------------------------------------------------------------
// Kernel 1: fused front end.
//   blocks [0,384):  QKV projection via MFMA on bf16 inputs.
//                    z = bx>>7 selects Q/K/V; V written TRANSPOSED (Vt[d][key'])
//                    with the permuted key layout (pos = 2*(loc&15)+(loc>>4)).
//   blocks [384,4480): geometric bias via table lerp -> biasP bf16,
//                    same key permutation.
// ---------------------------------------------------------------------------
__global__ __launch_bounds__(256) void fused_front(
    const unsigned short* __restrict__ xb, const float* __restrict__ pts,
    const unsigned short* __restrict__ wqb, const float* __restrict__ bq,
    const unsigned short* __restrict__ wkb, const float* __restrict__ bk,
    const unsigned short* __restrict__ wvb, const float* __restrict__ bv,
    const float* __restrict__ T,
    unsigned short* __restrict__ Qb, unsigned short* __restrict__ Kb,
    unsigned short* __restrict__ Vt, unsigned short* __restrict__ biasP)
{
    const int bx = blockIdx.x;
    const int t = threadIdx.x;

    if (bx < 384) {
        const int z  = bx >> 7;
        const int r0 = (bx & 127) << 4;
        const int w = t >> 6, lane = t & 63, quad = lane >> 4, c = lane & 15;
        const int c0 = w * 64;
        const unsigned short* Wm = (z == 0) ? wqb : (z == 1) ? wkb : wvb;
        const float* bia         = (z == 0) ? bq  : (z == 1) ? bk  : bv;

        f32x4 acc[4] = {};
        for (int kt = 0; kt < 8; ++kt) {
            bf16x8 a = *(const bf16x8*)(xb + (size_t)(r0 + c) * DM + kt * 32 + quad * 8);
#pragma unroll
            for (int ct = 0; ct < 4; ++ct) {
                bf16x8 b = *(const bf16x8*)(Wm + (size_t)(c0 + ct * 16 + c) * DM + kt * 32 + quad * 8);
                acc[ct] = __builtin_amdgcn_mfma_f32_16x16x32_bf16(a, b, acc[ct], 0, 0, 0);
            }
        }
        if (z < 2) {
            unsigned short* out = (z == 0) ? Qb : Kb;
#pragma unroll
            for (int ct = 0; ct < 4; ++ct) {
                float bc = bia[c0 + ct * 16 + c];
#pragma unroll
                for (int reg = 0; reg < 4; ++reg) {
                    int r = r0 + quad * 4 + reg;
                    out[(size_t)r * DM + c0 + ct * 16 + c] = f2bf(acc[ct][reg] + bc);
                }
            }
        } else {
            // V: write transposed with key permutation. Vt[col][pos], col = h*32+d.
#pragma unroll
            for (int ct = 0; ct < 4; ++ct) {
                int col = c0 + ct * 16 + c;
                float bc = bia[col];
#pragma unroll
                for (int reg = 0; reg < 4; ++reg) {
                    int key = r0 + quad * 4 + reg;
                    int loc = key & 31;
                    int pos = (key & ~31) + 2 * (loc & 15) + (loc >> 4);
                    Vt[(size_t)col * L_SEQ + pos] = f2bf(acc[ct][reg] + bc);
                }
            }
        }
    } else {
        const int b = bx - 384;
        const int i = b >> 1;
        const int p0 = ((b & 1) * 256 + t) * 4;
        const float xi = pts[i * 3], yi = pts[i * 3 + 1], zi = pts[i * 3 + 2];

        ushort4 o; unsigned short* po = (unsigned short*)&o;
#pragma unroll
        for (int v = 0; v < 4; ++v) {
            int p = p0 + v, loc = p & 31, base = p & ~31;
            int k = base + (loc >> 1) + 16 * (loc & 1);
            float dx = xi - pts[k * 3], dy = yi - pts[k * 3 + 1], dz = zi - pts[k * 3 + 2];
            float dist = sqrtf(dx * dx + dy * dy + dz * dz);
            float fn = dist * 256.0f;
            int n = (int)fn; n = (n > 4094) ? 4094 : n;
            float fr = fn - (float)n;
            float t0 = T[n], t1 = T[n + 1];
            po[v] = f2bf(fmaf(fr, t1 - t0, t0));
        }
        *(ushort4*)(biasP + (size_t)i * L_SEQ + p0) = o;
    }
}

// ---------------------------------------------------------------------------
// Kernel 2: MFMA flash attention. Block = (32 q-rows, 1 head), 4 waves with
// 4-way key split (512 keys each). Fixed-shift softmax (M=10) -> partials
// combine by plain sums. No __syncthreads in the K-loop; P does a wave-local
// LDS transpose (C-layout -> A-layout) in the permuted key order.
// ---------------------------------------------------------------------------
__global__ __launch_bounds__(256) void attn_mfma(
    const unsigned short* __restrict__ Qb, const unsigned short* __restrict__ Kb,
    const unsigned short* __restrict__ Vt, const unsigned short* __restrict__ biasP,
    unsigned short* __restrict__ Ab)
{
    __shared__ unsigned short Plds[4][32][40];
    __shared__ float Ol[4][32][36];
    __shared__ float Ll[4][32];
    const int t = threadIdx.x, w = t >> 6, lane = t & 63, quad = lane >> 4, c = lane & 15;
    const int h = blockIdx.y, r0 = blockIdx.x * 32;
    const int kbase = w * 512;
    const f32x4 Z = {};

    bf16x8 qf0 = *(const bf16x8*)(Qb + (size_t)(r0 + c) * DM + h * HD + quad * 8);
    bf16x8 qf1 = *(const bf16x8*)(Qb + (size_t)(r0 + 16 + c) * DM + h * HD + quad * 8);

    f32x4 O00 = {}, O01 = {}, O10 = {}, O11 = {};
    float l0[4] = {0.f,0.f,0.f,0.f}, l1[4] = {0.f,0.f,0.f,0.f};

    const float LOG2E = 1.4426950408889634f;
    const float C1 = 0.17677669529663687f * LOG2E;  // SCALE * log2e
    const float MC = -10.0f * LOG2E;                // fixed shift

    const unsigned short* Kp  = Kb + (size_t)h * HD + quad * 8;
    const unsigned short* Vp0 = Vt + (size_t)(h * HD + c) * L_SEQ + quad * 8;
    const unsigned short* Vp1 = Vt + (size_t)(h * HD + 16 + c) * L_SEQ + quad * 8;
    const int br0 = r0 + quad * 4;

    bf16x8 kf0 = *(const bf16x8*)(Kp + (size_t)(kbase + c) * DM);
    bf16x8 kf1 = *(const bf16x8*)(Kp + (size_t)(kbase + 16 + c) * DM);
    bf16x8 vf0 = *(const bf16x8*)(Vp0 + kbase);
    bf16x8 vf1 = *(const bf16x8*)(Vp1 + kbase);
    unsigned int bu0[4], bu1[4];
#pragma unroll
    for (int reg = 0; reg < 4; ++reg) {
        bu0[reg] = *(const unsigned int*)(biasP + (size_t)(br0 + reg) * L_SEQ + kbase + c * 2);
        bu1[reg] = *(const unsigned int*)(biasP + (size_t)(br0 + 16 + reg) * L_SEQ + kbase + c * 2);
    }

    for (int kt = 0; kt < 16; ++kt) {
        const int kn = kbase + (kt + 1) * 32;
        bf16x8 nk0 = kf0, nk1 = kf1, nv0 = vf0, nv1 = vf1;
        unsigned int nbu0[4], nbu1[4];
#pragma unroll
        for (int reg = 0; reg < 4; ++reg) { nbu0[reg] = bu0[reg]; nbu1[reg] = bu1[reg]; }
        if (kt < 15) {   // prefetch next tile's fragments (no barrier in this loop)
            nk0 = *(const bf16x8*)(Kp + (size_t)(kn + c) * DM);
            nk1 = *(const bf16x8*)(Kp + (size_t)(kn + 16 + c) * DM);
            nv0 = *(const bf16x8*)(Vp0 + kn);
            nv1 = *(const bf16x8*)(Vp1 + kn);
#pragma unroll
            for (int reg = 0; reg < 4; ++reg) {
                nbu0[reg] = *(const unsigned int*)(biasP + (size_t)(br0 + reg) * L_SEQ + kn + c * 2);
                nbu1[reg] = *(const unsigned int*)(biasP + (size_t)(br0 + 16 + reg) * L_SEQ + kn + c * 2);
            }
        }

        f32x4 S00 = __builtin_amdgcn_mfma_f32_16x16x32_bf16(qf0, kf0, Z, 0, 0, 0);
        f32x4 S01 = __builtin_amdgcn_mfma_f32_16x16x32_bf16(qf0, kf1, Z, 0, 0, 0);
        f32x4 S10 = __builtin_amdgcn_mfma_f32_16x16x32_bf16(qf1, kf0, Z, 0, 0, 0);
        f32x4 S11 = __builtin_amdgcn_mfma_f32_16x16x32_bf16(qf1, kf1, Z, 0, 0, 0);

#pragma unroll
        for (int reg = 0; reg < 4; ++reg) {
            unsigned int u = bu0[reg];
            float blo = __builtin_bit_cast(float, u << 16);
            float bhi = __builtin_bit_cast(float, u & 0xffff0000u);
            float p0 = __builtin_exp2f(fmaf(S00[reg], C1, fmaf(blo, LOG2E, MC)));
            float p1 = __builtin_exp2f(fmaf(S01[reg], C1, fmaf(bhi, LOG2E, MC)));
            l0[reg] += p0 + p1;
            unsigned int pb = __builtin_amdgcn_perm(
                __builtin_bit_cast(unsigned int, p1),
                __builtin_bit_cast(unsigned int, p0), 0x07060302);
            *(unsigned int*)&Plds[w][quad * 4 + reg][c * 2] = pb;

            u = bu1[reg];
            blo = __builtin_bit_cast(float, u << 16);
            bhi = __builtin_bit_cast(float, u & 0xffff0000u);
            p0 = __builtin_exp2f(fmaf(S10[reg], C1, fmaf(blo, LOG2E, MC)));
            p1 = __builtin_exp2f(fmaf(S11[reg], C1, fmaf(bhi, LOG2E, MC)));
            l1[reg] += p0 + p1;
            pb = __builtin_amdgcn_perm(
                __builtin_bit_cast(unsigned int, p1),
                __builtin_bit_cast(unsigned int, p0), 0x07060302);
            *(unsigned int*)&Plds[w][16 + quad * 4 + reg][c * 2] = pb;
        }

        bf16x8 pa0 = *(const bf16x8*)&Plds[w][c][quad * 8];
        bf16x8 pa1 = *(const bf16x8*)&Plds[w][16 + c][quad * 8];
        O00 = __builtin_amdgcn_mfma_f32_16x16x32_bf16(pa0, vf0, O00, 0, 0, 0);
        O01 = __builtin_amdgcn_mfma_f32_16x16x32_bf16(pa0, vf1, O01, 0, 0, 0);
        O10 = __builtin_amdgcn_mfma_f32_16x16x32_bf16(pa1, vf0, O10, 0, 0, 0);
        O11 = __builtin_amdgcn_mfma_f32_16x16x32_bf16(pa1, vf1, O11, 0, 0, 0);

        kf0 = nk0; kf1 = nk1; vf0 = nv0; vf1 = nv1;
#pragma unroll
        for (int reg = 0; reg < 4; ++reg) { bu0[reg] = nbu0[reg]; bu1[reg] = nbu1[reg]; }
    }

    // reduce l across the 16 lanes of each quad (rows live per (quad,reg))
#pragma unroll
    for (int off = 1; off < 16; off <<= 1) {
#pragma unroll
        for (int reg = 0; reg < 4; ++reg) {
            l0[reg] += __shfl_xor(l0[reg], off, 16);
            l1[reg] += __shfl_xor(l1[reg], off, 16);
        }
    }
    // dump per-wave partials (plain sums thanks to fixed shift)
#pragma unroll
    for (int reg = 0; reg < 4; ++reg) {
        int row = quad * 4 + reg;
        Ol[w][row][c]           = O00[reg];
        Ol[w][row][16 + c]      = O01[reg];
        Ol[w][row + 16][c]      = O10[reg];
        Ol[w][row + 16][16 + c] = O11[reg];
    }
    if (c == 0) {
#pragma unroll
        for (int reg = 0; reg < 4; ++reg) {
            Ll[w][quad * 4 + reg]      = l0[reg];
            Ll[w][quad * 4 + reg + 16] = l1[reg];
        }
    }
    __syncthreads();
    {
        int row = t >> 3, c4 = (t & 7) * 4;
        float4 a = *(const float4*)&Ol[0][row][c4];
        float4 b = *(const float4*)&Ol[1][row][c4];
        float4 d = *(const float4*)&Ol[2][row][c4];
        float4 e = *(const float4*)&Ol[3][row][c4];
        float inv = 1.0f / (Ll[0][row] + Ll[1][row] + Ll[2][row] + Ll[3][row]);
        ushort4 ob;
        ob.x = f2bf((a.x + b.x + d.x + e.x) * inv);
        ob.y = f2bf((a.y + b.y + d.y + e.y) * inv);
        ob.z = f2bf((a.z + b.z + d.z + e.z) * inv);
        ob.w = f2bf((a.w + b.w + d.w + e.w) * inv);
        *(ushort4*)(Ab + (size_t)(r0 + row) * DM + h * HD + c4) = ob;
    }
}

// ---------------------------------------------------------------------------
// Kernel 3: out-projection + bias + residual + LayerNorm, fused.
// Block = 16 rows x 256 cols (4 waves x 64 cols), bf16 weights from prep.
// ---------------------------------------------------------------------------
__global__ __launch_bounds__(256) void proj_ln(
    const unsigned short* __restrict__ Ab, const unsigned short* __restrict__ Wob,
    const float* __restrict__ bo, const float* __restrict__ feat,
    const float* __restrict__ ln_g, const float* __restrict__ ln_b,
    float* __restrict__ out)
{
    __shared__ float red1[4][16], red2[4][16];
    const int t = threadIdx.x, w = t >> 6, lane = t & 63, quad = lane >> 4, c = lane & 15;
    const int r0 = blockIdx.x * 16, c0 = w * 64;

    f32x4 acc[4] = {};
    for (int kt = 0; kt < 8; ++kt) {
        bf16x8 a = *(const bf16x8*)(Ab + (size_t)(r0 + c) * DM + kt * 32 + quad * 8);
#pragma unroll
        for (int ct = 0; ct < 4; ++ct) {
            bf16x8 b = *(const bf16x8*)(Wob + (size_t)(c0 + ct * 16 + c) * DM + kt * 32 + quad * 8);
            acc[ct] = __builtin_amdgcn_mfma_f32_16x16x32_bf16(a, b, acc[ct], 0, 0, 0);
        }
    }
    float y[4][4];
    float s1[4] = {0.f,0.f,0.f,0.f}, s2[4] = {0.f,0.f,0.f,0.f};
#pragma unroll
    for (int ct = 0; ct < 4; ++ct) {
        int col = c0 + ct * 16 + c;
        float bc = bo[col];
#pragma unroll
        for (int reg = 0; reg < 4; ++reg) {
            int r = r0 + quad * 4 + reg;
            float v = acc[ct][reg] + bc + feat[(size_t)r * DM + col];
            y[ct][reg] = v;
            s1[reg] += v; s2[reg] += v * v;
        }
    }
#pragma unroll
    for (int off = 1; off < 16; off <<= 1)
#pragma unroll
        for (int reg = 0; reg < 4; ++reg) {
            s1[reg] += __shfl_xor(s1[reg], off, 16);
            s2[reg] += __shfl_xor(s2[reg], off, 16);
        }
    if (c == 0)
#pragma unroll
        for (int reg = 0; reg < 4; ++reg) {
            red1[w][quad * 4 + reg] = s1[reg];
            red2[w][quad * 4 + reg] = s2[reg];
        }
    __syncthreads();
    float mu[4], rs[4];
#pragma unroll
    for (int reg = 0; reg < 4; ++reg) {
        int row = quad * 4 + reg;
        float a1 = red1[0][row] + red1[1][row] + red1[2][row] + red1[3][row];
        float a2 = red2[0][row] + red2[1][row] + red2[2][row] + red2[3][row];
        float m = a1 * (1.0f / 256.0f);
        mu[reg] = m;
        rs[reg] = rsqrtf(a2 * (1.0f / 256.0f) - m * m + 1e-5f);
    }
#pragma unroll
    for (int ct = 0; ct < 4; ++ct) {
        int col = c0 + ct * 16 + c;
        float g = ln_g[col], bb = ln_b[col];
#pragma unroll
        for (int reg = 0; reg < 4; ++reg) {
            int r = r0 + quad * 4 + reg;
            out[(size_t)r * DM + col] = (y[ct][reg] - mu[reg]) * rs[reg] * g + bb;
        }
    }
}

// ---------------------------------------------------------------------------
extern "C" void kernel_launch(void* const* d_in, const int* in_sizes, int n_in,
                              void* d_out, int out_size, void* d_ws, size_t ws_size,
                              hipStream_t stream) {
    (void)in_sizes; (void)n_in; (void)out_size; (void)ws_size;
    const float* features  = (const float*)d_in[0];
    const float* pointmaps = (const float*)d_in[1];
    const float* Wq = (const float*)d_in[2];  const float* bq = (const float*)d_in[3];
    const float* Wk = (const float*)d_in[4];  const float* bk = (const float*)d_in[5];
    const float* Wv = (const float*)d_in[6];  const float* bv = (const float*)d_in[7];
    const float* Wo = (const float*)d_in[8];  const float* bo = (const float*)d_in[9];
    const float* beta = (const float*)d_in[10];
    const float* k_w1 = (const float*)d_in[11]; const float* k_b1 = (const float*)d_in[12];
    const float* k_w2 = (const float*)d_in[13]; const float* k_b2 = (const float*)d_in[14];
    const float* ln_g = (const float*)d_in[15]; const float* ln_b = (const float*)d_in[16];
    float* out = (float*)d_out;

    char* W = (char*)d_ws;
    unsigned short* xb    = (unsigned short*)(W);             // 1 MB
    unsigned short* Wqb   = (unsigned short*)(W + 1048576);   // 128 KB
    unsigned short* Wkb   = (unsigned short*)(W + 1179648);
    unsigned short* Wvb   = (unsigned short*)(W + 1310720);
    unsigned short* Wob   = (unsigned short*)(W + 1441792);
    float*          T     = (float*)        (W + 1572864);    // 16 KB
    unsigned short* Qb    = (unsigned short*)(W + 1589248);   // 1 MB
    unsigned short* Kb    = (unsigned short*)(W + 2637824);
    unsigned short* Vt    = (unsigned short*)(W + 3686400);
    unsigned short* Ab    = (unsigned short*)(W + 4734976);
    unsigned short* biasP = (unsigned short*)(W + 5783552);   // 8 MB, ends 14.2 MB

    prep       <<<400, 256, 0, stream>>>(features, Wq, Wk, Wv, Wo,
                                         k_w1, k_b1, k_w2, k_b2, beta,
                                         xb, Wqb, Wkb, Wvb, Wob, T);
    fused_front<<<4480, 256, 0, stream>>>(xb, pointmaps,
                                          Wqb, bq, Wkb, bk, Wvb, bv, T,
                                          Qb, Kb, Vt, biasP);
    attn_mfma  <<<dim3(64, 8), 256, 0, stream>>>(Qb, Kb, Vt, biasP, Ab);
    proj_ln    <<<128,         256, 0, stream>>>(Ab, Wob, bo, features, ln_g, ln_b, out);
}